// Round 9
// baseline (352107.593 us; speedup 1.0000x reference)
//
#include <hip/hip_runtime.h>
#include <stdint.h>

typedef unsigned long long u64;
typedef float f32x32 __attribute__((ext_vector_type(32)));
typedef float f32x16 __attribute__((ext_vector_type(16)));

#define T_TOTAL 65536
#define ISZ 256
#define HSZ 512
#define NWORK 16
#define SLICE 32   // HSZ / NWORK
#define CTHR 512   // compute threads
#define NTHR 576   // + 64 service threads (1 wave)

// LDS skew (word index): +4 words per row -> max 2-way bank aliasing (free).
__device__ __forceinline__ int HSW(int i) { return i + ((i >> 5) << 2); }  // rows of 32
__device__ __forceinline__ int XSW(int i) { return i + ((i >> 4) << 2); }  // rows of 16

struct Ctl { int grank; int chosen; int fastctr; int done; int slowctr; int pad[11]; };

// Poll = genuine TCC-executed atomic RMW (add 0, sc0 returns old value).
// Inline asm so InstCombine cannot demote the idempotent RMW to an atomic
// LOAD (load-path polls read stale data on gfx950 — R3/R4/R5/R7 evidence).
// Compute threads' vmcnt queue contains ONLY this RMW, so the vmcnt(0) here
// waits ~one L2-atomic latency, not an HBM store drain (the R8 chain killer).
__device__ __forceinline__ u64 poll1_rmw(u64* p, unsigned sv, long long& budget) {
  u64 q, zero = 0;
  for (;;) {
    asm volatile("global_atomic_add_x2 %0, %1, %2, off sc0\n\t"
                 "s_waitcnt vmcnt(0)"
                 : "=&v"(q) : "v"(p), "v"(zero) : "memory");
    if ((unsigned)(q >> 32) == sv) break;
    if (--budget <= 0) break;
  }
  return q;
}
__device__ __forceinline__ void publish_rmw(u64* p, u64 v) {
  asm volatile("global_atomic_swap_x2 %0, %1, off" :: "v"(p), "v"(v) : "memory");
}

// ---------------------------------------------------------------------------
// Persistent fused GRU scan, 16 blocks x (512 compute + 64 service) threads.
//
// R8 post-mortem: the scan is LATENCY-chain bound, and the chain was bloated
// by vmcnt in-order retirement: the epilogue wave's poll vmcnt(0) drained its
// own out[]-HBM store + publish swap + x prefetch every step. This version
// gives compute waves a CLEAN vmem queue (poll RMW only) and moves all
// fire-and-forget traffic (publish swaps, out[] stores, x staging) to a
// dedicated service wave, handed off through LDS (hq).
//
// Sync: tagged 64-bit slots {tag=version, f32 value}, 16B-padded, parity-2
// ring. FAST mode (16 workers verified on ONE XCD): TCC atomic RMWs.
// SLOW fallback: agent-scope acquire/release (R2-proven).
//
// Barriers: B2 (h polled -> LDS ready) and B3 (hnew in hq ready; also
// orders x_lds/h_lds buffer turnover). Parity double-buffering of h_lds and
// x_lds as in R6/R8; service hq read at iter s+1 is separated from the
// epilogue's hq write at iter s by B3(s), and from the overwrite at iter s+1
// by B2(s+1). Spin fuse bounds worst-case runtime (fail, never wedge).
// ---------------------------------------------------------------------------
__global__ __launch_bounds__(NTHR, 1) void gru_fused(
    const float* __restrict__ xs, const float* __restrict__ w_ih,
    const float* __restrict__ w_hh, const float* __restrict__ bias,
    const float* __restrict__ bias_n, u64* __restrict__ hslot,
    Ctl* __restrict__ ctl, float* __restrict__ out) {
  const int tid = threadIdx.x;
  const bool is_svc = tid >= CTHR;
  const int svc = tid - CTHR;       // 0..63 for service wave
  const int seg = tid & 15;         // compute: K-segment
  const int rg  = tid >> 4;         // compute: unit within slice (0..31)

  __shared__ int s_role, s_fast;
  __shared__ __align__(16) float x_lds[2][320];
  __shared__ __align__(16) float h_lds[2][576];
  __shared__ float hq[32];          // epilogue -> service handoff (h_{s+1})

  // ---- election: verify 16 blocks on one XCD, else agent-scope fallback
  if (tid == 0) {
    unsigned xcc = 0;
    asm volatile("s_getreg_b32 %0, hwreg(HW_REG_XCC_ID)" : "=s"(xcc));
    long long eb = 100000000;
    int rank = __hip_atomic_fetch_add(&ctl->grank, 1, __ATOMIC_RELAXED,
                                      __HIP_MEMORY_SCOPE_AGENT);
    if (rank == 0)
      __hip_atomic_store(&ctl->chosen, (int)xcc + 1, __ATOMIC_RELEASE,
                         __HIP_MEMORY_SCOPE_AGENT);
    int chosen;
    do { chosen = __hip_atomic_load(&ctl->chosen, __ATOMIC_ACQUIRE,
                                    __HIP_MEMORY_SCOPE_AGENT); }
    while (chosen == 0 && --eb > 0);
    int fr = -1;
    if ((int)xcc == chosen - 1)
      fr = __hip_atomic_fetch_add(&ctl->fastctr, 1, __ATOMIC_RELAXED,
                                  __HIP_MEMORY_SCOPE_AGENT);
    __hip_atomic_fetch_add(&ctl->done, 1, __ATOMIC_ACQ_REL,
                           __HIP_MEMORY_SCOPE_AGENT);
    int dn;
    do { dn = __hip_atomic_load(&ctl->done, __ATOMIC_ACQUIRE,
                                __HIP_MEMORY_SCOPE_AGENT); }
    while (dn < (int)gridDim.x && --eb > 0);
    int fc = __hip_atomic_load(&ctl->fastctr, __ATOMIC_ACQUIRE,
                               __HIP_MEMORY_SCOPE_AGENT);
    int fast = (fc >= NWORK && dn >= (int)gridDim.x) ? 1 : 0;
    int role = -1;
    if (fast) {
      if (fr >= 0 && fr < NWORK) role = fr;
    } else {
      int sr = __hip_atomic_fetch_add(&ctl->slowctr, 1, __ATOMIC_RELAXED,
                                      __HIP_MEMORY_SCOPE_AGENT);
      if (sr < NWORK) role = sr;
    }
    s_role = role; s_fast = fast;
  }
  __syncthreads();
  const int role = s_role;   // uniform per block
  const int fast = s_fast;
  if (role < 0) return;      // whole block exits together

  // ---- compute threads: weights into true VGPRs (static indexing) ----
  f32x32 wh0, wh1, wh2;
  f32x16 wi0, wi1, wi2;
  float br = 0.f, bz = 0.f, bnn = 0.f, bn2 = 0.f;
  const int myunit = role * SLICE + (rg & 31);
  if (!is_svc) {
    const float* h0 = w_hh + (size_t)(0 * HSZ + myunit) * HSZ + seg * 32;
    const float* h1 = w_hh + (size_t)(1 * HSZ + myunit) * HSZ + seg * 32;
    const float* h2 = w_hh + (size_t)(2 * HSZ + myunit) * HSZ + seg * 32;
#pragma unroll
    for (int u = 0; u < 8; ++u) {
      float4 a = *(const float4*)(h0 + u * 4);
      float4 b = *(const float4*)(h1 + u * 4);
      float4 c = *(const float4*)(h2 + u * 4);
      wh0[u*4+0]=a.x; wh0[u*4+1]=a.y; wh0[u*4+2]=a.z; wh0[u*4+3]=a.w;
      wh1[u*4+0]=b.x; wh1[u*4+1]=b.y; wh1[u*4+2]=b.z; wh1[u*4+3]=b.w;
      wh2[u*4+0]=c.x; wh2[u*4+1]=c.y; wh2[u*4+2]=c.z; wh2[u*4+3]=c.w;
    }
    const float* i0 = w_ih + (size_t)(0 * HSZ + myunit) * ISZ + seg * 16;
    const float* i1 = w_ih + (size_t)(1 * HSZ + myunit) * ISZ + seg * 16;
    const float* i2 = w_ih + (size_t)(2 * HSZ + myunit) * ISZ + seg * 16;
#pragma unroll
    for (int u = 0; u < 4; ++u) {
      float4 a = *(const float4*)(i0 + u * 4);
      float4 b = *(const float4*)(i1 + u * 4);
      float4 c = *(const float4*)(i2 + u * 4);
      wi0[u*4+0]=a.x; wi0[u*4+1]=a.y; wi0[u*4+2]=a.z; wi0[u*4+3]=a.w;
      wi1[u*4+0]=b.x; wi1[u*4+1]=b.y; wi1[u*4+2]=b.z; wi1[u*4+3]=b.w;
      wi2[u*4+0]=c.x; wi2[u*4+1]=c.y; wi2[u*4+2]=c.z; wi2[u*4+3]=c.w;
    }
    br  = bias[myunit];
    bz  = bias[HSZ + myunit];
    bnn = bias[2 * HSZ + myunit];
    bn2 = bias_n[myunit];
  }

  // ---- service regs: x pipeline (xregA/B hold x[s+1] alternately) ----
  float4 xregA{}, xregB{};
  if (is_svc) {
    float4 t0 = *(const float4*)(xs + svc * 4);            // x[0]
    *(float4*)&x_lds[0][XSW(svc * 4)] = t0;
    xregA = *(const float4*)(xs + (size_t)ISZ + svc * 4);  // x[1]
  }
  __syncthreads();

  long long budget = 20000000;  // spin fuse (fail visibly, never wedge)

  // Loop body; XW = reg holding x[s+1] (to LDS now), XL = reg for x[s+2].
  auto step = [&](int s, float4& XW, float4& XL) {
    const int cur = s & 1, nxt = cur ^ 1;
    if (is_svc) {
      // (b) x[s+1] -> LDS (vmcnt wait here covers only last-iter's load: free)
      *(float4*)&x_lds[nxt][XSW(svc * 4)] = XW;
      // (a) publish h_s + store out row s-1 (s>0; h_0 is pre-zeroed slots)
      if (s > 0 && svc < 32) {
        float hv = hq[svc];
        u64 pw = ((u64)(unsigned)s << 32) | (u64)__float_as_uint(hv);
        u64* pp = &hslot[(size_t)cur * (HSZ * 2) + 2 * (role * SLICE + svc)];
        if (fast) publish_rmw(pp, pw);
        else __hip_atomic_store(pp, pw, __ATOMIC_RELEASE, __HIP_MEMORY_SCOPE_AGENT);
        out[(size_t)HSZ + (size_t)(s - 1) * HSZ + role * SLICE + svc] = hv;
      }
      // (c) issue x[s+2] load; used next iter (wait deferred a full step)
      int srow = (s + 2 < T_TOTAL) ? (s + 2) : (T_TOTAL - 1);
      XL = *(const float4*)(xs + (size_t)srow * ISZ + svc * 4);
    }
    float a0 = 0.f, a1 = 0.f, a2 = 0.f, a3 = 0.f;
    if (!is_svc) {
      // Input-side gate dots (independent of h). a3 = hidden-side n.
#pragma unroll
      for (int u = 0; u < 4; ++u) {
        float4 xv = *(const float4*)&x_lds[cur][XSW(seg * 16 + u * 4)];
        a0 += wi0[u*4+0]*xv.x + wi0[u*4+1]*xv.y + wi0[u*4+2]*xv.z + wi0[u*4+3]*xv.w;
        a1 += wi1[u*4+0]*xv.x + wi1[u*4+1]*xv.y + wi1[u*4+2]*xv.z + wi1[u*4+3]*xv.w;
        a2 += wi2[u*4+0]*xv.x + wi2[u*4+1]*xv.y + wi2[u*4+2]*xv.z + wi2[u*4+3]*xv.w;
      }
      // Poll h version s (1 slot/thread; clean vmem queue).
      u64* sb = hslot + (size_t)cur * (HSZ * 2);
      u64 q0;
      if (fast) {
        q0 = poll1_rmw(&sb[2 * tid], (unsigned)s, budget);
      } else {
        do {
          q0 = __hip_atomic_load(&sb[2 * tid], __ATOMIC_ACQUIRE,
                                 __HIP_MEMORY_SCOPE_AGENT);
        } while ((unsigned)(q0 >> 32) != (unsigned)s && --budget > 0);
      }
      h_lds[cur][HSW(tid)] = __uint_as_float((unsigned)q0);
    }
    __syncthreads();  // B2: h ready
    if (!is_svc) {
      // Hidden-side dots (critical chain): 3 rows x 32-wide segment.
#pragma unroll
      for (int u = 0; u < 8; ++u) {
        float4 hv = *(const float4*)&h_lds[cur][HSW(seg * 32 + u * 4)];
        a0 += wh0[u*4+0]*hv.x + wh0[u*4+1]*hv.y + wh0[u*4+2]*hv.z + wh0[u*4+3]*hv.w;
        a1 += wh1[u*4+0]*hv.x + wh1[u*4+1]*hv.y + wh1[u*4+2]*hv.z + wh1[u*4+3]*hv.w;
        a3 += wh2[u*4+0]*hv.x + wh2[u*4+1]*hv.y + wh2[u*4+2]*hv.z + wh2[u*4+3]*hv.w;
      }
#pragma unroll
      for (int p = 0; p < 4; ++p) {
        int m = 1 << p;
        a0 += __shfl_xor(a0, m, 64);
        a1 += __shfl_xor(a1, m, 64);
        a2 += __shfl_xor(a2, m, 64);
        a3 += __shfl_xor(a3, m, 64);
      }
      if (seg == 0) {  // one lane per unit: epilogue -> hq (LDS only!)
        float r  = 1.f / (1.f + __expf(-(br + a0)));
        float z  = 1.f / (1.f + __expf(-(bz + a1)));
        float tv = bnn + a2 + r * (a3 + bn2);
        float nn = 1.f - 2.f / (__expf(2.f * tv) + 1.f);
        float hold = h_lds[cur][HSW(myunit)];
        hq[rg] = nn + z * (hold - nn);
      }
    }
    __syncthreads();  // B3: hq ready for service; buffer turnover fence
  };

  for (int s = 0; s < T_TOTAL; s += 2) {  // 2x unroll: static reg pipeline
    step(s,     xregA, xregB);
    step(s + 1, xregB, xregA);
  }

  // Tail: hq holds h_T -> out row T-1 and final state (after last B3).
  if (is_svc && svc < 32) {
    float hv = hq[svc];
    out[(size_t)HSZ + (size_t)(T_TOTAL - 1) * HSZ + role * SLICE + svc] = hv;
    out[role * SLICE + svc] = hv;
  }
}

// ---------------------------------------------------------------------------
extern "C" void kernel_launch(void* const* d_in, const int* in_sizes, int n_in,
                              void* d_out, int out_size, void* d_ws, size_t ws_size,
                              hipStream_t stream) {
  const float* xs     = (const float*)d_in[0];
  const float* w_ih   = (const float*)d_in[1];
  const float* w_hh   = (const float*)d_in[2];
  const float* bias   = (const float*)d_in[3];
  const float* bias_n = (const float*)d_in[4];
  float* out   = (float*)d_out;
  u64*   hslot = (u64*)d_ws;                    // [2][1024] padded slots = 16 KB
  Ctl*   ctl   = (Ctl*)((char*)d_ws + 16384);   // election control

  hipMemsetAsync(d_ws, 0, 16384 + 256, stream); // tags=0 => h_0 = 0; ctl = 0
  gru_fused<<<256, NTHR, 0, stream>>>(xs, w_ih, w_hh, bias, bias_n, hslot, ctl, out);
}